// Round 11
// baseline (167.324 us; speedup 1.0000x reference)
//
#include <hip/hip_runtime.h>
#include <hip/hip_bf16.h>

#define BB 2048
#define AA 96
#define NIN 128
#define NHID 64
#define MI 4                 // 16-atom tiles per wave; 768 blocks = 3/CU, one round

typedef __attribute__((ext_vector_type(8))) short bf16x8;
typedef __attribute__((ext_vector_type(4))) float f32x4;
typedef __attribute__((address_space(1))) const unsigned g_u32;
typedef __attribute__((address_space(3))) unsigned l_u32;

static __device__ __forceinline__ unsigned short f2bf(float x) {
    unsigned u = __builtin_bit_cast(unsigned, x);
    return (unsigned short)((u + 0x7FFFu + ((u >> 16) & 1u)) >> 16);
}
static __device__ __forceinline__ unsigned cvt_pk_hw(float a, float b) {
    __hip_bfloat162 h = __float22bfloat162_rn(make_float2(a, b));
    unsigned u; __builtin_memcpy(&u, &h, 4);
    return u;
}

// ws image (16896 B): [0,16384) bf16 W1 frag image (fid=(s*4+t)*64+lane,
// lane elems k=s*32+(lane>>4)*8+j, n=t*16+(lane&15)); [16384) b1; [16640) w2.
__global__ void prep_kernel(const float* __restrict__ w1,
                            const float* __restrict__ b1,
                            const float* __restrict__ w2,
                            unsigned char* __restrict__ ws) {
    const int gid = blockIdx.x * 256 + threadIdx.x;
    if (gid < 1024) {
        const int lane = gid & 63, st = gid >> 6;
        const int s = st >> 2, t = st & 3;
        const int k0 = s * 32 + (lane >> 4) * 8;
        const int n  = t * 16 + (lane & 15);
        unsigned short o[8];
        #pragma unroll
        for (int j = 0; j < 8; ++j) o[j] = f2bf(w1[(k0 + j) * NHID + n]);
        uint4 v; __builtin_memcpy(&v, o, 16);
        ((uint4*)ws)[gid] = v;
    } else if (gid < 1088) {
        ((float*)(ws + 16384))[gid - 1024] = b1[gid - 1024];
    } else if (gid < 1152) {
        ((float*)(ws + 16640))[gid - 1088] = w2[gid - 1088];
    }
}

// R11: rep staged by global_load_lds width-16 (contiguous 1KB/instr — R3-R10's
// 16B-granule stride-512 pattern capped at ~3.5 TB/s, see R4). DMA lane-XOR
// swizzle (lane ^ chunk&7) makes frag ds_read_b128 8-lanes-per-bank-group =
// b128-optimal. Wave-private buffers: no barrier in tile loop; next-tile DMA
// issued before MFMA. Layouts validated R6-R10 (absmax 0.0625).
__global__ __launch_bounds__(256) void atomwise_kernel(
    const float* __restrict__ rep,
    const int*   __restrict__ zs,
    const float* __restrict__ mask,
    const unsigned char* __restrict__ ws,
    const float* __restrict__ b2,
    const float* __restrict__ aref,
    const float* __restrict__ mean,
    const float* __restrict__ stddev,
    float* __restrict__ out)
{
    // [0,16384) W1 frags | [16384) b1 | [16640) w2 | [16896 + wv*8192) rep bufs
    __shared__ __align__(16) unsigned char smem[49664];

    const int tid  = threadIdx.x;
    const int lane = tid & 63;
    const int wv   = tid >> 6;
    const int nl   = lane & 15;
    const int quad = lane >> 4;

    unsigned char* mybuf = smem + 16896 + wv * 8192;
    const int wave_atom0 = (blockIdx.x * 4 + wv) * (16 * MI);

    // ---- stage W1 image -> LDS (linear uint4 copy, conflict-free)
    {
        const uint4* src = (const uint4*)ws;
        uint4*       dst = (uint4*)smem;
        #pragma unroll
        for (int i = 0; i < 4; ++i) dst[tid + i * 256] = src[tid + i * 256];
        if (tid < 32) dst[1024 + tid] = src[1024 + tid];
    }

    // ---- epilogue operands for all MI tiles, prefetched once
    float mqs[MI], arefs[MI];
    #pragma unroll
    for (int mt = 0; mt < MI; ++mt) {
        const int ag = wave_atom0 + mt * 16 + quad * 4 + (nl & 3);
        mqs[mt]   = mask[ag];
        arefs[mt] = aref[zs[ag]];
    }

    // ---- tile 0 DMA: chunk d = 1KB contiguous, lane-XOR swizzled
    {
        const unsigned* gsrc = (const unsigned*)(rep + (size_t)wave_atom0 * NIN);
        #pragma unroll
        for (int d = 0; d < 8; ++d)
            __builtin_amdgcn_global_load_lds(
                (g_u32*)(gsrc + d * 256 + ((lane ^ d) << 2)),
                (l_u32*)(mybuf + d * 1024), 16, 0, 0);
    }
    __syncthreads();   // W1 image ready (also drains tile-0 DMA)

    const bf16x8* w1f = (const bf16x8*)smem;
    const float*  b1s = (const float*)(smem + 16384);
    const float*  w2s = (const float*)(smem + 16640);

    const float sdv  = stddev[0];
    const float cadd = fmaf(b2[0], sdv, mean[0]);
    const float LOG2E = 1.4426950408889634f;
    const float LN2   = 0.6931471805599453f;

    // frag-read geometry: granule G = (nl&1)*32 + 8s + 2q + h in chunk nl>>1,
    // stored at slot G^ (chunk&7)
    const int dbase = nl >> 1;
    const unsigned char* rdbase = mybuf + dbase * 1024;
    const int gb = ((nl & 1) << 5) | (quad << 1);

    #pragma unroll
    for (int mt = 0; mt < MI; ++mt) {
        const int atom0 = wave_atom0 + mt * 16;

        __builtin_amdgcn_s_waitcnt(0);   // this tile's DMA landed in mybuf

        union { bf16x8 v; unsigned u[4]; } fa[4];
        #pragma unroll
        for (int s = 0; s < 4; ++s) {
            const int g0 = gb + 8 * s;
            const float4 f0 = *(const float4*)(rdbase + (((g0    ) ^ dbase) << 4));
            const float4 f1 = *(const float4*)(rdbase + (((g0 + 1) ^ dbase) << 4));
            fa[s].u[0] = cvt_pk_hw(f0.x, f0.y);
            fa[s].u[1] = cvt_pk_hw(f0.z, f0.w);
            fa[s].u[2] = cvt_pk_hw(f1.x, f1.y);
            fa[s].u[3] = cvt_pk_hw(f1.z, f1.w);
        }

        // prefetch next tile into the (now frag-consumed) buffer
        if (mt + 1 < MI) {
            const unsigned* gsrc = (const unsigned*)(rep + (size_t)(atom0 + 16) * NIN);
            #pragma unroll
            for (int d = 0; d < 8; ++d)
                __builtin_amdgcn_global_load_lds(
                    (g_u32*)(gsrc + d * 256 + ((lane ^ d) << 2)),
                    (l_u32*)(mybuf + d * 1024), 16, 0, 0);
        }

        f32x4 acc[4];
        #pragma unroll
        for (int t = 0; t < 4; ++t) acc[t] = (f32x4){0.f, 0.f, 0.f, 0.f};
        #pragma unroll
        for (int s = 0; s < 4; ++s) {
            const bf16x8* fr = &w1f[s * 256 + lane];
            #pragma unroll
            for (int t = 0; t < 4; ++t)
                acc[t] = __builtin_amdgcn_mfma_f32_16x16x32_bf16(fa[s].v, fr[t * 64], acc[t], 0, 0, 0);
        }

        // softplus + dot(w2) + reduce; 1 atomic/tile (16 | 96)
        float v[4];
        #pragma unroll
        for (int r = 0; r < 4; ++r) {
            float p = 0.f;
            #pragma unroll
            for (int t = 0; t < 4; ++t) {
                float x  = acc[t][r] + b1s[t * 16 + nl];
                float ax = fabsf(x);
                float em = exp2f(-ax * LOG2E);
                float sp = fmaxf(x, 0.f) + log2f(1.f + em) * LN2;
                p = fmaf(sp - LN2, w2s[t * 16 + nl], p);
            }
            p += __shfl_xor(p, 1); p += __shfl_xor(p, 2);
            p += __shfl_xor(p, 4); p += __shfl_xor(p, 8);
            v[r] = p;
        }
        const int rsel = nl & 3;
        float vr = v[0];
        vr = rsel == 1 ? v[1] : vr;
        vr = rsel == 2 ? v[2] : vr;
        vr = rsel == 3 ? v[3] : vr;
        float contrib = (nl < 4) ? mqs[mt] * (fmaf(vr, sdv, cadd) + arefs[mt]) : 0.f;
        #pragma unroll
        for (int off = 32; off; off >>= 1) contrib += __shfl_xor(contrib, off);
        if (lane == 0) atomicAdd(out + atom0 / AA, contrib);
    }
}

extern "C" void kernel_launch(void* const* d_in, const int* in_sizes, int n_in,
                              void* d_out, int out_size, void* d_ws, size_t ws_size,
                              hipStream_t stream) {
    const float* rep    = (const float*)d_in[0];
    const int*   zs     = (const int*)  d_in[1];
    const float* mask   = (const float*)d_in[2];
    const float* w1     = (const float*)d_in[3];
    const float* b1     = (const float*)d_in[4];
    const float* w2     = (const float*)d_in[5];
    const float* b2     = (const float*)d_in[6];
    const float* aref   = (const float*)d_in[7];
    const float* mean   = (const float*)d_in[8];
    const float* stddev = (const float*)d_in[9];
    float* out = (float*)d_out;
    unsigned char* ws = (unsigned char*)d_ws;

    (void)hipMemsetAsync(out, 0, (size_t)out_size * sizeof(float), stream);

    prep_kernel<<<dim3(5), dim3(256), 0, stream>>>(w1, b1, w2, ws);

    const int blocks = (BB * AA) / (4 * 16 * MI);   // 768 = 3 blocks/CU, one round
    atomwise_kernel<<<dim3(blocks), dim3(256), 0, stream>>>(
        rep, zs, mask, ws, b2, aref, mean, stddev, out);
}